// Round 3
// baseline (263.442 us; speedup 1.0000x reference)
//
#include <hip/hip_runtime.h>

// H = hidden size = 512, fixed by the problem.
#define H 512

// Native vector type usable with __builtin_nontemporal_store.
typedef float floatx4 __attribute__((ext_vector_type(4)));

// Output layout (flat f32, reference return order):
//   h_out      [H]        @ 0
//   y_out      [H]        @ 512
//   jac_W_hh   [H,H,H]    @ 1024
//   jac_W_ih   [H,H,H]    @ 1024 + H^3
//   jac_b      [H,H]      @ 1024 + 2*H^3
//   dynamics   [H,H]      @ 1024 + 2*H^3 + H^2
static constexpr long long JSZ      = (long long)H * H * H;
static constexpr long long OFF_H    = 0;
static constexpr long long OFF_Y    = H;
static constexpr long long OFF_JWHH = 2 * H;
static constexpr long long OFF_JWIH = OFF_JWHH + JSZ;
static constexpr long long OFF_JB   = OFF_JWHH + 2 * JSZ;
static constexpr long long OFF_DYN  = OFF_JB + (long long)H * H;

// ---------------------------------------------------------------------------
// 1) Zero-fill jac_W_hh + jac_W_ih + jac_b (contiguous, ~1.0748 GB).
//    Nontemporal float4 streaming stores; this is the write roofline.
__global__ void zero_kernel(floatx4* __restrict__ p, long long n4) {
    long long i = (long long)blockIdx.x * blockDim.x + threadIdx.x;
    long long stride = (long long)gridDim.x * blockDim.x;
    const floatx4 z = {0.f, 0.f, 0.f, 0.f};
    for (; i < n4; i += stride)
        __builtin_nontemporal_store(z, &p[i]);
}

// ---------------------------------------------------------------------------
// 2) Fused per-row kernel: block i (128 threads, one float4/thread) does
//    - th = tanh(h_prev) in shared
//    - h_out[i] = W_hh[i,:]@th + W_ih[i,:]@x + b[i] + pert[i];  th2[i]=tanh(h_out[i])
//    - dynamics[i,:]   = W_hh[i,:] * (1-th^2)      (W_hh row already loaded)
//    - jac_W_hh[i,i,:] = th
//    - jac_W_ih[i,i,:] = x
//    - jac_b[i,i]      = 1
__global__ void fused_row_kernel(const float* __restrict__ h_prev,
                                 const float* __restrict__ x,
                                 const float* __restrict__ pert,
                                 const float* __restrict__ W_hh,
                                 const float* __restrict__ W_ih,
                                 const float* __restrict__ b,
                                 float* __restrict__ out,
                                 float* __restrict__ ws_th2) {
    int i = blockIdx.x;    // 512 blocks
    int t = threadIdx.x;   // 128 threads

    __shared__ float sth[H];
    for (int j = t; j < H; j += 128) sth[j] = tanhf(h_prev[j]);
    __syncthreads();

    const float4 wh  = ((const float4*)(W_hh + (long long)i * H))[t];
    const float4 wi  = ((const float4*)(W_ih + (long long)i * H))[t];
    const float4 xv  = ((const float4*)x)[t];
    const float4 thv = ((const float4*)sth)[t];

    // dynamics row i
    float4 dynv;
    dynv.x = wh.x * (1.f - thv.x * thv.x);
    dynv.y = wh.y * (1.f - thv.y * thv.y);
    dynv.z = wh.z * (1.f - thv.z * thv.z);
    dynv.w = wh.w * (1.f - thv.w * thv.w);
    ((float4*)(out + OFF_DYN + (long long)i * H))[t] = dynv;

    // jacobian diagonal rows (overwrite zeros laid down by zero_kernel)
    long long rowoff = (long long)i * ((long long)H * H + H);
    ((float4*)(out + OFF_JWHH + rowoff))[t] = thv;
    ((float4*)(out + OFF_JWIH + rowoff))[t] = xv;
    if (t == 0) out[OFF_JB + (long long)i * (H + 1)] = 1.0f;

    // h matvec partial
    float acc = wh.x * thv.x + wh.y * thv.y + wh.z * thv.z + wh.w * thv.w
              + wi.x * xv.x  + wi.y * xv.y  + wi.z * xv.z  + wi.w * xv.w;
    __shared__ float sm[128];
    sm[t] = acc;
    __syncthreads();
    for (int s = 64; s > 0; s >>= 1) {
        if (t < s) sm[t] += sm[t + s];
        __syncthreads();
    }
    if (t == 0) {
        float h = sm[0] + b[i] + pert[i];
        out[OFF_H + i] = h;
        ws_th2[i] = tanhf(h);
    }
}

// ---------------------------------------------------------------------------
// 3) y_out[i] = C_w[i,:]@tanh(h_out) + D_w[i,:]@x
__global__ void ymatvec_kernel(const float* __restrict__ C_w,
                               const float* __restrict__ D_w,
                               const float* __restrict__ x,
                               const float* __restrict__ th2,
                               float* __restrict__ out) {
    int i = blockIdx.x;    // 512 blocks
    int t = threadIdx.x;   // 128 threads
    const float4 cw = ((const float4*)(C_w + (long long)i * H))[t];
    const float4 dw = ((const float4*)(D_w + (long long)i * H))[t];
    const float4 xv = ((const float4*)x)[t];
    const float4 tv = ((const float4*)th2)[t];
    float acc = cw.x * tv.x + cw.y * tv.y + cw.z * tv.z + cw.w * tv.w
              + dw.x * xv.x + dw.y * xv.y + dw.z * xv.z + dw.w * xv.w;
    __shared__ float sm[128];
    sm[t] = acc;
    __syncthreads();
    for (int s = 64; s > 0; s >>= 1) {
        if (t < s) sm[t] += sm[t + s];
        __syncthreads();
    }
    if (t == 0) out[OFF_Y + i] = sm[0];
}

// ---------------------------------------------------------------------------
extern "C" void kernel_launch(void* const* d_in, const int* in_sizes, int n_in,
                              void* d_out, int out_size, void* d_ws, size_t ws_size,
                              hipStream_t stream) {
    const float* h_prev = (const float*)d_in[0];
    const float* x      = (const float*)d_in[1];
    const float* pert   = (const float*)d_in[2];
    const float* W_hh   = (const float*)d_in[3];
    const float* W_ih   = (const float*)d_in[4];
    const float* b      = (const float*)d_in[5];
    const float* C_w    = (const float*)d_in[6];
    const float* D_w    = (const float*)d_in[7];
    float* out = (float*)d_out;
    float* ws  = (float*)d_ws;   // ws[0..511] = tanh(h_out)

    // Zero jac_W_hh + jac_W_ih + jac_b (2*H^3 + H^2 floats, contiguous).
    long long n4 = (2 * JSZ + (long long)H * H) / 4;
    zero_kernel<<<4096, 256, 0, stream>>>((floatx4*)(out + OFF_JWHH), n4);

    fused_row_kernel<<<H, 128, 0, stream>>>(h_prev, x, pert, W_hh, W_ih, b, out, ws);
    ymatvec_kernel<<<H, 128, 0, stream>>>(C_w, D_w, x, ws, out);
}

// Round 4
// 177.267 us; speedup vs baseline: 1.4861x; 1.4861x over previous
//
#include <hip/hip_runtime.h>

// H = hidden size = 512, fixed by the problem.
#define H 512

// Output layout (flat f32, reference return order):
//   h_out      [H]        @ 0
//   y_out      [H]        @ 512
//   jac_W_hh   [H,H,H]    @ 1024
//   jac_W_ih   [H,H,H]    @ 1024 + H^3
//   jac_b      [H,H]      @ 1024 + 2*H^3
//   dynamics   [H,H]      @ 1024 + 2*H^3 + H^2
static constexpr long long JSZ      = (long long)H * H * H;
static constexpr long long OFF_H    = 0;
static constexpr long long OFF_Y    = H;
static constexpr long long OFF_JWHH = 2 * H;
static constexpr long long OFF_JWIH = OFF_JWHH + JSZ;
static constexpr long long OFF_JB   = OFF_JWHH + 2 * JSZ;
static constexpr long long OFF_DYN  = OFF_JB + (long long)H * H;

__device__ inline float wave_reduce_sum(float v) {
    #pragma unroll
    for (int off = 32; off > 0; off >>= 1)
        v += __shfl_down(v, off, 64);
    return v;
}

// ---------------------------------------------------------------------------
// Fused per-row kernel: block i (128 threads = 2 waves, one float4/thread):
//    - th = tanh(h_prev) in shared
//    - h_out[i] = W_hh[i,:]@th + W_ih[i,:]@x + b[i] + pert[i];  th2[i]=tanh(h_out[i])
//    - dynamics[i,:]   = W_hh[i,:] * (1-th^2)
//    - jac_W_hh[i,i,:] = th ; jac_W_ih[i,i,:] = x ; jac_b[i,i] = 1
__global__ void fused_row_kernel(const float* __restrict__ h_prev,
                                 const float* __restrict__ x,
                                 const float* __restrict__ pert,
                                 const float* __restrict__ W_hh,
                                 const float* __restrict__ W_ih,
                                 const float* __restrict__ b,
                                 float* __restrict__ out,
                                 float* __restrict__ ws_th2) {
    int i = blockIdx.x;    // 512 blocks
    int t = threadIdx.x;   // 128 threads

    __shared__ float sth[H];
    for (int j = t; j < H; j += 128) sth[j] = tanhf(h_prev[j]);
    __syncthreads();

    const float4 wh  = ((const float4*)(W_hh + (long long)i * H))[t];
    const float4 wi  = ((const float4*)(W_ih + (long long)i * H))[t];
    const float4 xv  = ((const float4*)x)[t];
    const float4 thv = ((const float4*)sth)[t];

    // dynamics row i
    float4 dynv;
    dynv.x = wh.x * (1.f - thv.x * thv.x);
    dynv.y = wh.y * (1.f - thv.y * thv.y);
    dynv.z = wh.z * (1.f - thv.z * thv.z);
    dynv.w = wh.w * (1.f - thv.w * thv.w);
    ((float4*)(out + OFF_DYN + (long long)i * H))[t] = dynv;

    // jacobian diagonal rows (overwrite zeros laid down by the memset)
    long long rowoff = (long long)i * ((long long)H * H + H);
    ((float4*)(out + OFF_JWHH + rowoff))[t] = thv;
    ((float4*)(out + OFF_JWIH + rowoff))[t] = xv;
    if (t == 0) out[OFF_JB + (long long)i * (H + 1)] = 1.0f;

    // h matvec: per-thread partial -> wave shuffle reduce -> cross-wave via LDS
    float acc = wh.x * thv.x + wh.y * thv.y + wh.z * thv.z + wh.w * thv.w
              + wi.x * xv.x  + wi.y * xv.y  + wi.z * xv.z  + wi.w * xv.w;
    acc = wave_reduce_sum(acc);
    __shared__ float sm[2];
    if ((t & 63) == 0) sm[t >> 6] = acc;
    __syncthreads();
    if (t == 0) {
        float h = sm[0] + sm[1] + b[i] + pert[i];
        out[OFF_H + i] = h;
        ws_th2[i] = tanhf(h);
    }
}

// ---------------------------------------------------------------------------
// y_out[i] = C_w[i,:]@tanh(h_out) + D_w[i,:]@x
__global__ void ymatvec_kernel(const float* __restrict__ C_w,
                               const float* __restrict__ D_w,
                               const float* __restrict__ x,
                               const float* __restrict__ th2,
                               float* __restrict__ out) {
    int i = blockIdx.x;    // 512 blocks
    int t = threadIdx.x;   // 128 threads
    const float4 cw = ((const float4*)(C_w + (long long)i * H))[t];
    const float4 dw = ((const float4*)(D_w + (long long)i * H))[t];
    const float4 xv = ((const float4*)x)[t];
    const float4 tv = ((const float4*)th2)[t];
    float acc = cw.x * tv.x + cw.y * tv.y + cw.z * tv.z + cw.w * tv.w
              + dw.x * xv.x + dw.y * xv.y + dw.z * xv.z + dw.w * xv.w;
    acc = wave_reduce_sum(acc);
    __shared__ float sm[2];
    if ((t & 63) == 0) sm[t >> 6] = acc;
    __syncthreads();
    if (t == 0) out[OFF_Y + i] = sm[0] + sm[1];
}

// ---------------------------------------------------------------------------
extern "C" void kernel_launch(void* const* d_in, const int* in_sizes, int n_in,
                              void* d_out, int out_size, void* d_ws, size_t ws_size,
                              hipStream_t stream) {
    const float* h_prev = (const float*)d_in[0];
    const float* x      = (const float*)d_in[1];
    const float* pert   = (const float*)d_in[2];
    const float* W_hh   = (const float*)d_in[3];
    const float* W_ih   = (const float*)d_in[4];
    const float* b      = (const float*)d_in[5];
    const float* C_w    = (const float*)d_in[6];
    const float* D_w    = (const float*)d_in[7];
    float* out = (float*)d_out;
    float* ws  = (float*)d_ws;   // ws[0..511] = tanh(h_out)

    // Bulk-zero jac_W_hh + jac_W_ih + jac_b (contiguous, 1.0748 GB) with the
    // runtime's tuned fill kernel (measured 6.3-6.6 TB/s on this chip).
    size_t zero_bytes = (size_t)(2 * JSZ + (long long)H * H) * sizeof(float);
    hipMemsetAsync(out + OFF_JWHH, 0, zero_bytes, stream);

    fused_row_kernel<<<H, 128, 0, stream>>>(h_prev, x, pert, W_hh, W_ih, b, out, ws);
    ymatvec_kernel<<<H, 128, 0, stream>>>(C_w, D_w, x, ws, out);
}